// Round 4
// baseline (395.418 us; speedup 1.0000x reference)
//
#include <hip/hip_runtime.h>
#include <hip/hip_bf16.h>

#define Bn 8
#define Cn 256
#define Hn 128
#define Wn 128
#define On 256
#define HWn (Hn*Wn)
#define Pn  HWn           // 16384 positions per batch
#define Rn  786           // 768 deform rows (k*256+o) + 18 offset rows
#define Rpad 896          // 7 * 128 GEMM N-tiles
#define GROW 800          // G2 row length in elements (row = one q)
#define QC  ((size_t)Pn * Cn)

typedef __attribute__((ext_vector_type(8))) short bf16x8;
typedef __attribute__((ext_vector_type(4))) float f32x4;

__device__ __forceinline__ void gload_lds16(const void* g, void* l) {
  __builtin_amdgcn_global_load_lds(
      (__attribute__((address_space(1))) void*)g,
      (__attribute__((address_space(3))) void*)l, 16, 0, 0);
}

__device__ __forceinline__ unsigned short f2bf(float f) {
  unsigned int u = __float_as_uint(f);
  unsigned int r = (u + 0x7fffu + ((u >> 16) & 1u)) >> 16;
  return (unsigned short)r;
}
__device__ __forceinline__ float bf2f(unsigned short u) {
  return __uint_as_float(((unsigned int)u) << 16);
}

// -------- Phase 0: build W_big[r][c] bf16, r = k*256+o (deform) | 768+oc*3+kw (offset), pad->896 --------
__global__ __launch_bounds__(256) void k_wprep(
    const float* __restrict__ dw, const float* __restrict__ ow,
    unsigned short* __restrict__ Wbig) {
  int r = blockIdx.x;          // 0..895
  int c = threadIdx.x;         // 0..255
  float v = 0.f;
  if (r < 768) {
    int k = r >> 8, o = r & 255;
    v = dw[((size_t)o * Cn + c) * 3 + k];
  } else if (r < Rn) {
    int rr = r - 768;
    int oc = rr / 3, kw = rr - 3 * oc;
    v = ow[((size_t)oc * Cn + c) * 3 + kw];
  }
  Wbig[(size_t)r * Cn + c] = f2bf(v);
}

// -------- Phase 1: transpose+cast  xbT[z][q][c] bf16 <- x[b][c][q] fp32 --------
__global__ __launch_bounds__(256) void k_transpose(
    const float* __restrict__ x, unsigned short* __restrict__ xbT, int b0) {
  int b = b0 + blockIdx.z;
  int q0 = blockIdx.x * 64, c0 = blockIdx.y * 64;
  __shared__ unsigned short t[64][66];
  int tid = threadIdx.x;
  int qi = tid & 63, cg = tid >> 6;
  const float* xb = x + (size_t)b * Cn * HWn;
  #pragma unroll
  for (int i = 0; i < 16; ++i) {
    int cl = i * 4 + cg;
    t[cl][qi] = f2bf(xb[(size_t)(c0 + cl) * HWn + q0 + qi]);
  }
  __syncthreads();
  unsigned short* dst = xbT + (size_t)blockIdx.z * QC;
  int c2 = (tid & 31) * 2, qg = tid >> 5;
  #pragma unroll
  for (int j = 0; j < 8; ++j) {
    int ql = j * 8 + qg;
    unsigned int u = (unsigned int)t[c2][ql] | ((unsigned int)t[c2 + 1][ql] << 16);
    *(unsigned int*)(dst + (size_t)(q0 + ql) * Cn + c0 + c2) = u;
  }
}

// -------- Phase 2: GEMM  G2[q][r] = sum_c xbT[q][c] * Wbig[r][c]  (bf16 out) --------
// grid: x = r-tile (7, fastest -> A-tile shared across consecutive blocks), y = q-tile, z = batch
__global__ __launch_bounds__(256) void k_gemmG(
    const unsigned short* __restrict__ xbT,
    const unsigned short* __restrict__ Wbig,
    unsigned short* __restrict__ G2) {
  int r0 = blockIdx.x * 128;
  int q0 = blockIdx.y * 128;
  const unsigned short* xb = xbT + (size_t)blockIdx.z * QC;
  unsigned short* Gz = G2 + (size_t)blockIdx.z * Pn * GROW;
  __shared__ unsigned short Qs[128 * 64];    // [q][64c] swizzled (A-operand)
  __shared__ unsigned short Ws[128 * 64];    // [r][64c] swizzled (B-operand)
  int tid = threadIdx.x;
  int lane = tid & 63, wid = tid >> 6;
  int wr = wid >> 1, wc = wid & 1;           // wr: q-half, wc: r-half
  f32x4 acc[4][4];
  #pragma unroll
  for (int m = 0; m < 4; ++m)
    #pragma unroll
    for (int n = 0; n < 4; ++n) acc[m][n] = (f32x4){0.f, 0.f, 0.f, 0.f};

  for (int kt = 0; kt < 4; ++kt) {
    int ck0 = kt * 64;
    __syncthreads();
    #pragma unroll
    for (int i = 0; i < 4; ++i) {
      int fo = wid * 1024 + i * 4096 + lane * 16;
      int row = fo >> 7;
      int slot = (fo >> 4) & 7;
      int ss = slot ^ (row & 7);             // pre-swizzle SOURCE (rule 21)
      gload_lds16(xb   + (size_t)(q0 + row) * Cn + ck0 + ss * 8, (char*)Qs + fo);
      gload_lds16(Wbig + (size_t)(r0 + row) * Cn + ck0 + ss * 8, (char*)Ws + fo);
    }
    __syncthreads();
    #pragma unroll
    for (int s = 0; s < 2; ++s) {
      bf16x8 af[4], bfr[4];
      #pragma unroll
      for (int m = 0; m < 4; ++m) {
        int row = wr * 64 + m * 16 + (lane & 15);
        int slot = (s * 4 + (lane >> 4)) ^ (row & 7);
        af[m] = *(const bf16x8*)((const char*)Qs + row * 128 + slot * 16);
      }
      #pragma unroll
      for (int n = 0; n < 4; ++n) {
        int row = wc * 64 + n * 16 + (lane & 15);
        int slot = (s * 4 + (lane >> 4)) ^ (row & 7);
        bfr[n] = *(const bf16x8*)((const char*)Ws + row * 128 + slot * 16);
      }
      #pragma unroll
      for (int m = 0; m < 4; ++m)
        #pragma unroll
        for (int n = 0; n < 4; ++n)
          acc[m][n] = __builtin_amdgcn_mfma_f32_16x16x32_bf16(af[m], bfr[n], acc[m][n], 0, 0, 0);
    }
  }
  // D rows = q (A-operand), cols = r (B-operand)
  bool tail = (r0 + 128 > Rn);
  if (!tail) {
    #pragma unroll
    for (int m = 0; m < 4; ++m)
      #pragma unroll
      for (int n = 0; n < 4; ++n)
        #pragma unroll
        for (int rr = 0; rr < 4; ++rr) {
          int q = q0 + wr * 64 + m * 16 + (lane >> 4) * 4 + rr;
          int r = r0 + wc * 64 + n * 16 + (lane & 15);
          Gz[(size_t)q * GROW + r] = f2bf(acc[m][n][rr]);
        }
  } else {
    #pragma unroll
    for (int m = 0; m < 4; ++m)
      #pragma unroll
      for (int n = 0; n < 4; ++n)
        #pragma unroll
        for (int rr = 0; rr < 4; ++rr) {
          int q = q0 + wr * 64 + m * 16 + (lane >> 4) * 4 + rr;
          int r = r0 + wc * 64 + n * 16 + (lane & 15);
          if (r < Rn) Gz[(size_t)q * GROW + r] = f2bf(acc[m][n][rr]);
        }
  }
}

// -------- Phase 3: epilogue  out[b][o][p] = sum_k sum_corner wgt * G2[q_corner][k*256+o] --------
__global__ __launch_bounds__(256) void k_epilogue(
    const unsigned short* __restrict__ G2, const float* __restrict__ obias,
    float* __restrict__ out, int b0) {
  int z = blockIdx.z;
  int b = b0 + z;
  const char* Gb = (const char*)(G2 + (size_t)z * Pn * GROW);
  int p0 = blockIdx.x * 64;
  int o0 = blockIdx.y * 64;
  int ho = p0 >> 7, wo0 = p0 & 127;

  __shared__ float Sw[64][3][4];
  __shared__ int   Sq[64][3][4];
  int tid = threadIdx.x;
  if (tid < 192) {
    int pl = tid & 63, k = tid >> 6;
    int wo = wo0 + pl;
    float offy = 0.f, offx = 0.f;
    int ocy = 2 * k, ocx = 2 * k + 1;
    if (ocy != 4) {
      float s = obias[ocy];
      #pragma unroll
      for (int kw = 0; kw < 3; ++kw) {
        int col = wo + kw - 1;
        if (col >= 0 && col < Wn)
          s += bf2f(*(const unsigned short*)(Gb + ((size_t)(ho * Wn + col) * GROW + 768 + ocy * 3 + kw) * 2));
      }
      offy = s;
    }
    if (ocx != 1) {
      float s = obias[ocx];
      #pragma unroll
      for (int kw = 0; kw < 3; ++kw) {
        int col = wo + kw - 1;
        if (col >= 0 && col < Wn)
          s += bf2f(*(const unsigned short*)(Gb + ((size_t)(ho * Wn + col) * GROW + 768 + ocx * 3 + kw) * 2));
      }
      offx = s;
    }
    float py = (float)ho + offy;
    float px = (float)(wo + k - 1) + offx;
    float y0f = floorf(py), x0f = floorf(px);
    float wy = py - y0f, wx = px - x0f;
    int y0 = (int)y0f, x0 = (int)x0f;
    int y1 = y0 + 1, x1 = x0 + 1;
    bool vy0 = (y0 >= 0) && (y0 < Hn), vy1 = (y1 >= 0) && (y1 < Hn);
    bool vx0 = (x0 >= 0) && (x0 < Wn), vx1 = (x1 >= 0) && (x1 < Wn);
    float w00 = (vy0 && vx0) ? (1.f - wy) * (1.f - wx) : 0.f;
    float w01 = (vy0 && vx1) ? (1.f - wy) * wx : 0.f;
    float w10 = (vy1 && vx0) ? wy * (1.f - wx) : 0.f;
    float w11 = (vy1 && vx1) ? wy * wx : 0.f;
    int yc0 = min(max(y0, 0), Hn - 1), yc1 = min(max(y1, 0), Hn - 1);
    int xc0 = min(max(x0, 0), Wn - 1), xc1 = min(max(x1, 0), Wn - 1);
    Sq[pl][k][0] = (yc0 * Wn + xc0) * (GROW * 2) + k * 512;
    Sq[pl][k][1] = (yc0 * Wn + xc1) * (GROW * 2) + k * 512;
    Sq[pl][k][2] = (yc1 * Wn + xc0) * (GROW * 2) + k * 512;
    Sq[pl][k][3] = (yc1 * Wn + xc1) * (GROW * 2) + k * 512;
    Sw[pl][k][0] = w00; Sw[pl][k][1] = w01; Sw[pl][k][2] = w10; Sw[pl][k][3] = w11;
  }
  __syncthreads();

  int pl = tid & 63, og = tid >> 6;
  float w[3][4]; int qb[3][4];
  #pragma unroll
  for (int k = 0; k < 3; ++k)
    #pragma unroll
    for (int cc = 0; cc < 4; ++cc) { w[k][cc] = Sw[pl][k][cc]; qb[k][cc] = Sq[pl][k][cc]; }

  float* op = out + ((size_t)b * On) * Pn + p0 + pl;
  #pragma unroll
  for (int oi = 0; oi < 2; ++oi) {
    int ob8 = o0 + og * 16 + oi * 8;       // octet base o
    float a8[8];
    #pragma unroll
    for (int e = 0; e < 8; ++e) a8[e] = 0.f;
    #pragma unroll
    for (int k = 0; k < 3; ++k)
      #pragma unroll
      for (int cc = 0; cc < 4; ++cc) {
        bf16x8 v = *(const bf16x8*)(Gb + qb[k][cc] + ob8 * 2);
        float wv = w[k][cc];
        #pragma unroll
        for (int e = 0; e < 8; ++e)
          a8[e] += wv * bf2f((unsigned short)v[e]);
      }
    #pragma unroll
    for (int e = 0; e < 8; ++e)
      op[(size_t)(ob8 + e) * Pn] = a8[e];
  }
}

extern "C" void kernel_launch(void* const* d_in, const int* in_sizes, int n_in,
                              void* d_out, int out_size, void* d_ws, size_t ws_size,
                              hipStream_t stream) {
  const float* x  = (const float*)d_in[0];
  const float* ow = (const float*)d_in[1];
  const float* ob = (const float*)d_in[2];
  const float* dw = (const float*)d_in[3];
  float* out = (float*)d_out;

  char* ws = (char*)d_ws;
  size_t wbig_bytes = (size_t)Rpad * Cn * 2;            // 459 KB
  size_t wbig_al = (wbig_bytes + 255) & ~(size_t)255;
  size_t xbT_bytes = QC * 2;                            // 8.39 MB / batch
  size_t g2_bytes  = (size_t)Pn * GROW * 2;             // 26.2 MB / batch

  int nb = 1;
  if (ws_size >= wbig_al + 8 * (xbT_bytes + g2_bytes)) nb = 8;
  else if (ws_size >= wbig_al + 4 * (xbT_bytes + g2_bytes)) nb = 4;
  else if (ws_size >= wbig_al + 2 * (xbT_bytes + g2_bytes)) nb = 2;

  unsigned short* Wbig = (unsigned short*)ws;
  unsigned short* xbT  = (unsigned short*)(ws + wbig_al);
  unsigned short* G2   = (unsigned short*)(ws + wbig_al + (size_t)nb * xbT_bytes);

  k_wprep<<<Rpad, 256, 0, stream>>>(dw, ow, Wbig);
  for (int b0 = 0; b0 < Bn; b0 += nb) {
    k_transpose<<<dim3(256, 4, nb), 256, 0, stream>>>(x, xbT, b0);
    k_gemmG<<<dim3(7, 128, nb), 256, 0, stream>>>(xbT, Wbig, G2);
    k_epilogue<<<dim3(256, 4, nb), 256, 0, stream>>>(G2, ob, out, b0);
  }
}

// Round 5
// 241.398 us; speedup vs baseline: 1.6380x; 1.6380x over previous
//
#include <hip/hip_runtime.h>
#include <hip/hip_bf16.h>

#define Bn 8
#define Cn 256
#define Hn 128
#define Wn 128
#define On 256
#define HWn (Hn*Wn)
#define Pn  HWn           // 16384 positions per batch
#define Rpad 896          // Wbig rows (768 deform unused here + 18 offset + pad)
#define W2ROW 768         // W2 row length (ck)
#define QC  ((size_t)Pn * Cn)

typedef __attribute__((ext_vector_type(8))) short bf16x8;
typedef __attribute__((ext_vector_type(4))) float f32x4;

__device__ __forceinline__ void gload_lds16(const void* g, void* l) {
  __builtin_amdgcn_global_load_lds(
      (__attribute__((address_space(1))) void*)g,
      (__attribute__((address_space(3))) void*)l, 16, 0, 0);
}

__device__ __forceinline__ unsigned short f2bf(float f) {
  unsigned int u = __float_as_uint(f);
  unsigned int r = (u + 0x7fffu + ((u >> 16) & 1u)) >> 16;
  return (unsigned short)r;
}
__device__ __forceinline__ float bf2f(unsigned short u) {
  return __uint_as_float(((unsigned int)u) << 16);
}
__device__ __forceinline__ void bacc(uint4 v, float w, float* f) {
  f[0] += w * __uint_as_float(v.x << 16);
  f[1] += w * __uint_as_float(v.x & 0xffff0000u);
  f[2] += w * __uint_as_float(v.y << 16);
  f[3] += w * __uint_as_float(v.y & 0xffff0000u);
  f[4] += w * __uint_as_float(v.z << 16);
  f[5] += w * __uint_as_float(v.z & 0xffff0000u);
  f[6] += w * __uint_as_float(v.w << 16);
  f[7] += w * __uint_as_float(v.w & 0xffff0000u);
}

// -------- Phase 0: W2[o][k*256+c] = dw[o][c][k]; Wbig[768+oc*3+kw][c] = ow[oc][c][kw] --------
__global__ __launch_bounds__(256) void k_wprep(
    const float* __restrict__ dw, const float* __restrict__ ow,
    unsigned short* __restrict__ W2, unsigned short* __restrict__ Wbig) {
  int r = blockIdx.x;          // 0..895
  int c = threadIdx.x;         // 0..255
  float v = 0.f;
  if (r < 768) {
    int k = r >> 8, o = r & 255;
    v = dw[((size_t)o * Cn + c) * 3 + k];
    W2[(size_t)o * W2ROW + k * 256 + c] = f2bf(v);
  } else if (r < 786) {
    int rr = r - 768;
    int oc = rr / 3, kw = rr - 3 * oc;
    v = ow[((size_t)oc * Cn + c) * 3 + kw];
  }
  Wbig[(size_t)r * Cn + c] = f2bf(v);
}

// -------- Phase 1: transpose+cast  xbT[z][q][c] bf16 <- x[b][c][q] fp32 --------
__global__ __launch_bounds__(256) void k_transpose(
    const float* __restrict__ x, unsigned short* __restrict__ xbT) {
  int b = blockIdx.z;
  int q0 = blockIdx.x * 64, c0 = blockIdx.y * 64;
  __shared__ unsigned short t[64][66];
  int tid = threadIdx.x;
  int qi = tid & 63, cg = tid >> 6;
  const float* xb = x + (size_t)b * Cn * HWn;
  #pragma unroll
  for (int i = 0; i < 16; ++i) {
    int cl = i * 4 + cg;
    t[cl][qi] = f2bf(xb[(size_t)(c0 + cl) * HWn + q0 + qi]);
  }
  __syncthreads();
  unsigned short* dst = xbT + (size_t)b * QC;
  int c2 = (tid & 31) * 2, qg = tid >> 5;
  #pragma unroll
  for (int j = 0; j < 8; ++j) {
    int ql = j * 8 + qg;
    unsigned int u = (unsigned int)t[c2][ql] | ((unsigned int)t[c2 + 1][ql] << 16);
    *(unsigned int*)(dst + (size_t)(q0 + ql) * Cn + c0 + c2) = u;
  }
}

// -------- Phase 2: Goff[z][q][j] = sum_c xbT[q][c] * Wbig[768+j][c], j<18 (bf16) --------
__global__ __launch_bounds__(256) void k_goff(
    const unsigned short* __restrict__ xbT,
    const unsigned short* __restrict__ Wbig,
    unsigned short* __restrict__ Goff) {
  int q0 = blockIdx.y * 128;
  const unsigned short* xb = xbT + (size_t)blockIdx.z * QC;
  unsigned short* Gz = Goff + (size_t)blockIdx.z * Pn * 32;
  __shared__ unsigned short Qs[128 * 64];
  __shared__ unsigned short Ws[128 * 64];
  int tid = threadIdx.x;
  int lane = tid & 63, wid = tid >> 6;
  int wr = wid >> 1, wc = wid & 1;
  f32x4 acc[4][4];
  #pragma unroll
  for (int m = 0; m < 4; ++m)
    #pragma unroll
    for (int n = 0; n < 4; ++n) acc[m][n] = (f32x4){0.f, 0.f, 0.f, 0.f};

  for (int kt = 0; kt < 4; ++kt) {
    int ck0 = kt * 64;
    __syncthreads();
    #pragma unroll
    for (int i = 0; i < 4; ++i) {
      int fo = wid * 1024 + i * 4096 + lane * 16;
      int row = fo >> 7;
      int slot = (fo >> 4) & 7;
      int ss = slot ^ (row & 7);
      gload_lds16(xb   + (size_t)(q0 + row) * Cn + ck0 + ss * 8, (char*)Qs + fo);
      gload_lds16(Wbig + (size_t)(768 + row) * Cn + ck0 + ss * 8, (char*)Ws + fo);
    }
    __syncthreads();
    #pragma unroll
    for (int s = 0; s < 2; ++s) {
      bf16x8 af[4], bfr[4];
      #pragma unroll
      for (int m = 0; m < 4; ++m) {
        int row = wr * 64 + m * 16 + (lane & 15);
        int slot = (s * 4 + (lane >> 4)) ^ (row & 7);
        af[m] = *(const bf16x8*)((const char*)Qs + row * 128 + slot * 16);
      }
      #pragma unroll
      for (int n = 0; n < 4; ++n) {
        int row = wc * 64 + n * 16 + (lane & 15);
        int slot = (s * 4 + (lane >> 4)) ^ (row & 7);
        bfr[n] = *(const bf16x8*)((const char*)Ws + row * 128 + slot * 16);
      }
      #pragma unroll
      for (int m = 0; m < 4; ++m)
        #pragma unroll
        for (int n = 0; n < 4; ++n)
          acc[m][n] = __builtin_amdgcn_mfma_f32_16x16x32_bf16(af[m], bfr[n], acc[m][n], 0, 0, 0);
    }
  }
  if (wc == 0) {
    #pragma unroll
    for (int m = 0; m < 4; ++m)
      #pragma unroll
      for (int n = 0; n < 2; ++n)
        #pragma unroll
        for (int rr = 0; rr < 4; ++rr) {
          int q = q0 + wr * 64 + m * 16 + (lane >> 4) * 4 + rr;
          int j = n * 16 + (lane & 15);
          if (j < 18) Gz[(size_t)q * 32 + j] = f2bf(acc[m][n][rr]);
        }
  }
}

// -------- Phase 3: fused sample+GEMM  out[b][o][p] = sum_ck bilinear(xbT)[p][ck] * W2[o][ck] --------
__global__ __launch_bounds__(256) void k_fgemm(
    const unsigned short* __restrict__ xbT,
    const unsigned short* __restrict__ W2,
    const unsigned short* __restrict__ Goff,
    const float* __restrict__ obias,
    float* __restrict__ out) {
  int ot = blockIdx.x, pt = blockIdx.y, z = blockIdx.z;
  int o0 = ot * 128;
  int ho = pt;                       // p-tile = one image row (128 positions)
  const unsigned short* xz = xbT + (size_t)z * QC;
  const unsigned short* Gf = Goff + (size_t)z * Pn * 32;

  __shared__ unsigned short Qs[128 * 64];   // W2 tile [o][64ck] swizzled
  __shared__ unsigned short Ss[128 * 64];   // sampled tile [p][64c] swizzled
  __shared__ float Sw4[128][3][4];
  __shared__ int   Sq4[128][3][4];          // corner row byte offsets (q*512)

  int tid = threadIdx.x;
  // ---- prologue: offsets -> bilinear weights + corner rows per (p,k) ----
  for (int t = tid; t < 384; t += 256) {
    int k = t >> 7;                 // 0..2
    int wo = t & 127;
    float offy = 0.f, offx = 0.f;
    int ocy = 2 * k, ocx = 2 * k + 1;
    if (ocy != 4) {
      float s = obias[ocy];
      #pragma unroll
      for (int kw = 0; kw < 3; ++kw) {
        int col = wo + kw - 1;
        if (col >= 0 && col < Wn)
          s += bf2f(Gf[(size_t)(ho * Wn + col) * 32 + ocy * 3 + kw]);
      }
      offy = s;
    }
    if (ocx != 1) {
      float s = obias[ocx];
      #pragma unroll
      for (int kw = 0; kw < 3; ++kw) {
        int col = wo + kw - 1;
        if (col >= 0 && col < Wn)
          s += bf2f(Gf[(size_t)(ho * Wn + col) * 32 + ocx * 3 + kw]);
      }
      offx = s;
    }
    float py = (float)ho + offy;
    float px = (float)(wo + k - 1) + offx;
    float y0f = floorf(py), x0f = floorf(px);
    float wy = py - y0f, wx = px - x0f;
    int y0 = (int)y0f, x0 = (int)x0f;
    int y1 = y0 + 1, x1 = x0 + 1;
    bool vy0 = (y0 >= 0) && (y0 < Hn), vy1 = (y1 >= 0) && (y1 < Hn);
    bool vx0 = (x0 >= 0) && (x0 < Wn), vx1 = (x1 >= 0) && (x1 < Wn);
    int yc0 = min(max(y0, 0), Hn - 1), yc1 = min(max(y1, 0), Hn - 1);
    int xc0 = min(max(x0, 0), Wn - 1), xc1 = min(max(x1, 0), Wn - 1);
    Sq4[wo][k][0] = (yc0 * Wn + xc0) * 512;
    Sq4[wo][k][1] = (yc0 * Wn + xc1) * 512;
    Sq4[wo][k][2] = (yc1 * Wn + xc0) * 512;
    Sq4[wo][k][3] = (yc1 * Wn + xc1) * 512;
    Sw4[wo][k][0] = (vy0 && vx0) ? (1.f - wy) * (1.f - wx) : 0.f;
    Sw4[wo][k][1] = (vy0 && vx1) ? (1.f - wy) * wx : 0.f;
    Sw4[wo][k][2] = (vy1 && vx0) ? wy * (1.f - wx) : 0.f;
    Sw4[wo][k][3] = (vy1 && vx1) ? wy * wx : 0.f;
  }

  int lane = tid & 63, wid = tid >> 6;
  int wr = wid >> 1, wc = wid & 1;          // wr: o-half, wc: p-half
  int oct = tid & 7, pg = tid >> 3;         // staging lanes: 8 octets x 32 p-groups
  f32x4 acc[4][4];
  #pragma unroll
  for (int m = 0; m < 4; ++m)
    #pragma unroll
    for (int n = 0; n < 4; ++n) acc[m][n] = (f32x4){0.f, 0.f, 0.f, 0.f};

  __syncthreads();   // Sw4/Sq4 ready

  for (int kt = 0; kt < 12; ++kt) {
    int k = kt >> 2;
    int c0 = (kt & 3) << 6;
    __syncthreads();                        // LDS free from previous MFMA reads
    // A: W2 o-rows via global_load_lds (issue early, hides under B staging VALU)
    #pragma unroll
    for (int i = 0; i < 4; ++i) {
      int fo = wid * 1024 + i * 4096 + lane * 16;
      int row = fo >> 7;
      int slot = (fo >> 4) & 7;
      int ss = slot ^ (row & 7);
      gload_lds16(W2 + (size_t)(o0 + row) * W2ROW + k * 256 + c0 + ss * 8, (char*)Qs + fo);
    }
    // B: bilinear-sampled p-rows, reg-staged, swizzled ds_write
    const char* bse = (const char*)xz + (c0 + oct * 8) * 2;
    #pragma unroll
    for (int i = 0; i < 4; ++i) {
      int pl = pg + 32 * i;
      float w0 = Sw4[pl][k][0], w1 = Sw4[pl][k][1], w2 = Sw4[pl][k][2], w3 = Sw4[pl][k][3];
      uint4 v0 = *(const uint4*)(bse + Sq4[pl][k][0]);
      uint4 v1 = *(const uint4*)(bse + Sq4[pl][k][1]);
      uint4 v2 = *(const uint4*)(bse + Sq4[pl][k][2]);
      uint4 v3 = *(const uint4*)(bse + Sq4[pl][k][3]);
      float f[8] = {0.f, 0.f, 0.f, 0.f, 0.f, 0.f, 0.f, 0.f};
      bacc(v0, w0, f); bacc(v1, w1, f); bacc(v2, w2, f); bacc(v3, w3, f);
      uint4 r;
      r.x = (unsigned int)f2bf(f[0]) | ((unsigned int)f2bf(f[1]) << 16);
      r.y = (unsigned int)f2bf(f[2]) | ((unsigned int)f2bf(f[3]) << 16);
      r.z = (unsigned int)f2bf(f[4]) | ((unsigned int)f2bf(f[5]) << 16);
      r.w = (unsigned int)f2bf(f[6]) | ((unsigned int)f2bf(f[7]) << 16);
      *(uint4*)((char*)Ss + pl * 128 + ((oct ^ (pl & 7)) << 4)) = r;
    }
    __syncthreads();                        // A landed + B written
    #pragma unroll
    for (int s = 0; s < 2; ++s) {
      bf16x8 af[4], bfr[4];
      #pragma unroll
      for (int m = 0; m < 4; ++m) {
        int row = wr * 64 + m * 16 + (lane & 15);
        int slot = (s * 4 + (lane >> 4)) ^ (row & 7);
        af[m] = *(const bf16x8*)((const char*)Qs + row * 128 + slot * 16);
      }
      #pragma unroll
      for (int n = 0; n < 4; ++n) {
        int row = wc * 64 + n * 16 + (lane & 15);
        int slot = (s * 4 + (lane >> 4)) ^ (row & 7);
        bfr[n] = *(const bf16x8*)((const char*)Ss + row * 128 + slot * 16);
      }
      #pragma unroll
      for (int m = 0; m < 4; ++m)
        #pragma unroll
        for (int n = 0; n < 4; ++n)
          acc[m][n] = __builtin_amdgcn_mfma_f32_16x16x32_bf16(af[m], bfr[n], acc[m][n], 0, 0, 0);
    }
  }
  // C write: D row = o (A-operand), col = p
  float* ob_ = out + (size_t)z * On * Pn;
  int p0 = pt * 128;
  #pragma unroll
  for (int m = 0; m < 4; ++m)
    #pragma unroll
    for (int n = 0; n < 4; ++n)
      #pragma unroll
      for (int rr = 0; rr < 4; ++rr) {
        int o = o0 + wr * 64 + m * 16 + (lane >> 4) * 4 + rr;
        int p = p0 + wc * 64 + n * 16 + (lane & 15);
        ob_[(size_t)o * Pn + p] = acc[m][n][rr];
      }
}

extern "C" void kernel_launch(void* const* d_in, const int* in_sizes, int n_in,
                              void* d_out, int out_size, void* d_ws, size_t ws_size,
                              hipStream_t stream) {
  const float* x  = (const float*)d_in[0];
  const float* ow = (const float*)d_in[1];
  const float* ob = (const float*)d_in[2];
  const float* dw = (const float*)d_in[3];
  float* out = (float*)d_out;

  char* ws = (char*)d_ws;
  size_t w2_bytes   = (size_t)On * W2ROW * 2;           // 384 KB
  size_t wbig_bytes = (size_t)Rpad * Cn * 2;            // 459 KB
  size_t xbT_bytes  = QC * 2;                           // 8.39 MB / batch
  size_t goff_bytes = (size_t)Pn * 32 * 2;              // 1.05 MB / batch
  size_t w2_al   = (w2_bytes + 255) & ~(size_t)255;
  size_t wbig_al = (wbig_bytes + 255) & ~(size_t)255;

  unsigned short* W2   = (unsigned short*)ws;
  unsigned short* Wbig = (unsigned short*)(ws + w2_al);
  unsigned short* xbT  = (unsigned short*)(ws + w2_al + wbig_al);
  unsigned short* Goff = (unsigned short*)(ws + w2_al + wbig_al + (size_t)Bn * xbT_bytes);
  (void)goff_bytes; (void)ws_size;

  k_wprep<<<Rpad, 256, 0, stream>>>(dw, ow, W2, Wbig);
  k_transpose<<<dim3(256, 4, Bn), 256, 0, stream>>>(x, xbT);
  k_goff<<<dim3(1, 128, Bn), 256, 0, stream>>>(xbT, Wbig, Goff);
  k_fgemm<<<dim3(2, 128, Bn), 256, 0, stream>>>(xbT, W2, Goff, ob, out);
}

// Round 6
// 184.037 us; speedup vs baseline: 2.1486x; 1.3117x over previous
//
#include <hip/hip_runtime.h>
#include <hip/hip_bf16.h>

#define Bn 8
#define Cn 256
#define Hn 128
#define Wn 128
#define On 256
#define HWn (Hn*Wn)
#define Pn  HWn           // 16384 positions per batch
#define Rpad 896          // Wbig rows (768 deform unused here + 18 offset + pad)
#define W2ROW 768         // W2 row length (ck)
#define QC  ((size_t)Pn * Cn)

typedef __attribute__((ext_vector_type(8))) short bf16x8;
typedef __attribute__((ext_vector_type(4))) float f32x4;

__device__ __forceinline__ void gload_lds16(const void* g, void* l) {
  __builtin_amdgcn_global_load_lds(
      (__attribute__((address_space(1))) void*)g,
      (__attribute__((address_space(3))) void*)l, 16, 0, 0);
}

__device__ __forceinline__ unsigned short f2bf(float f) {
  unsigned int u = __float_as_uint(f);
  unsigned int r = (u + 0x7fffu + ((u >> 16) & 1u)) >> 16;
  return (unsigned short)r;
}
__device__ __forceinline__ float bf2f(unsigned short u) {
  return __uint_as_float(((unsigned int)u) << 16);
}
__device__ __forceinline__ void bacc(uint4 v, float w, float* f) {
  f[0] += w * __uint_as_float(v.x << 16);
  f[1] += w * __uint_as_float(v.x & 0xffff0000u);
  f[2] += w * __uint_as_float(v.y << 16);
  f[3] += w * __uint_as_float(v.y & 0xffff0000u);
  f[4] += w * __uint_as_float(v.z << 16);
  f[5] += w * __uint_as_float(v.z & 0xffff0000u);
  f[6] += w * __uint_as_float(v.w << 16);
  f[7] += w * __uint_as_float(v.w & 0xffff0000u);
}

// -------- Phase 0: W2[o][k*256+c] = dw[o][c][k]; Wbig[768+oc*3+kw][c] = ow[oc][c][kw] --------
__global__ __launch_bounds__(256) void k_wprep(
    const float* __restrict__ dw, const float* __restrict__ ow,
    unsigned short* __restrict__ W2, unsigned short* __restrict__ Wbig) {
  int r = blockIdx.x;          // 0..895
  int c = threadIdx.x;         // 0..255
  float v = 0.f;
  if (r < 768) {
    int k = r >> 8, o = r & 255;
    v = dw[((size_t)o * Cn + c) * 3 + k];
    W2[(size_t)o * W2ROW + k * 256 + c] = f2bf(v);
  } else if (r < 786) {
    int rr = r - 768;
    int oc = rr / 3, kw = rr - 3 * oc;
    v = ow[((size_t)oc * Cn + c) * 3 + kw];
  }
  Wbig[(size_t)r * Cn + c] = f2bf(v);
}

// -------- Phase 1: transpose+cast  xbT[z][q][c] bf16 <- x[b][c][q] fp32 --------
__global__ __launch_bounds__(256) void k_transpose(
    const float* __restrict__ x, unsigned short* __restrict__ xbT) {
  int b = blockIdx.z;
  int q0 = blockIdx.x * 64, c0 = blockIdx.y * 64;
  __shared__ unsigned short t[64][66];
  int tid = threadIdx.x;
  int qi = tid & 63, cg = tid >> 6;
  const float* xb = x + (size_t)b * Cn * HWn;
  #pragma unroll
  for (int i = 0; i < 16; ++i) {
    int cl = i * 4 + cg;
    t[cl][qi] = f2bf(xb[(size_t)(c0 + cl) * HWn + q0 + qi]);
  }
  __syncthreads();
  unsigned short* dst = xbT + (size_t)b * QC;
  int c2 = (tid & 31) * 2, qg = tid >> 5;
  #pragma unroll
  for (int j = 0; j < 8; ++j) {
    int ql = j * 8 + qg;
    unsigned int u = (unsigned int)t[c2][ql] | ((unsigned int)t[c2 + 1][ql] << 16);
    *(unsigned int*)(dst + (size_t)(q0 + ql) * Cn + c0 + c2) = u;
  }
}

// -------- Phase 2: Goff[z][q][j] = sum_c xbT[q][c] * Wbig[768+j][c], j<18 (bf16) --------
__global__ __launch_bounds__(256) void k_goff(
    const unsigned short* __restrict__ xbT,
    const unsigned short* __restrict__ Wbig,
    unsigned short* __restrict__ Goff) {
  int q0 = blockIdx.y * 128;
  const unsigned short* xb = xbT + (size_t)blockIdx.z * QC;
  unsigned short* Gz = Goff + (size_t)blockIdx.z * Pn * 32;
  __shared__ unsigned short Qs[128 * 64];
  __shared__ unsigned short Ws[128 * 64];
  int tid = threadIdx.x;
  int lane = tid & 63, wid = tid >> 6;
  int wr = wid >> 1, wc = wid & 1;
  f32x4 acc[4][4];
  #pragma unroll
  for (int m = 0; m < 4; ++m)
    #pragma unroll
    for (int n = 0; n < 4; ++n) acc[m][n] = (f32x4){0.f, 0.f, 0.f, 0.f};

  for (int kt = 0; kt < 4; ++kt) {
    int ck0 = kt * 64;
    __syncthreads();
    #pragma unroll
    for (int i = 0; i < 4; ++i) {
      int fo = wid * 1024 + i * 4096 + lane * 16;
      int row = fo >> 7;
      int slot = (fo >> 4) & 7;
      int ss = slot ^ (row & 7);
      gload_lds16(xb   + (size_t)(q0 + row) * Cn + ck0 + ss * 8, (char*)Qs + fo);
      gload_lds16(Wbig + (size_t)(768 + row) * Cn + ck0 + ss * 8, (char*)Ws + fo);
    }
    __syncthreads();
    #pragma unroll
    for (int s = 0; s < 2; ++s) {
      bf16x8 af[4], bfr[4];
      #pragma unroll
      for (int m = 0; m < 4; ++m) {
        int row = wr * 64 + m * 16 + (lane & 15);
        int slot = (s * 4 + (lane >> 4)) ^ (row & 7);
        af[m] = *(const bf16x8*)((const char*)Qs + row * 128 + slot * 16);
      }
      #pragma unroll
      for (int n = 0; n < 4; ++n) {
        int row = wc * 64 + n * 16 + (lane & 15);
        int slot = (s * 4 + (lane >> 4)) ^ (row & 7);
        bfr[n] = *(const bf16x8*)((const char*)Ws + row * 128 + slot * 16);
      }
      #pragma unroll
      for (int m = 0; m < 4; ++m)
        #pragma unroll
        for (int n = 0; n < 4; ++n)
          acc[m][n] = __builtin_amdgcn_mfma_f32_16x16x32_bf16(af[m], bfr[n], acc[m][n], 0, 0, 0);
    }
  }
  if (wc == 0) {
    #pragma unroll
    for (int m = 0; m < 4; ++m)
      #pragma unroll
      for (int n = 0; n < 2; ++n)
        #pragma unroll
        for (int rr = 0; rr < 4; ++rr) {
          int q = q0 + wr * 64 + m * 16 + (lane >> 4) * 4 + rr;
          int j = n * 16 + (lane & 15);
          if (j < 18) Gz[(size_t)q * 32 + j] = f2bf(acc[m][n][rr]);
        }
  }
}

// -------- Phase 3: fused sample+GEMM, 8 waves, full O=256 per block --------
// out[b][o][ho*128+pc] = sum_ck bilinear(xbT)[p][ck] * W2[o][ck]
__global__ __launch_bounds__(512) void k_fgemm(
    const unsigned short* __restrict__ xbT,
    const unsigned short* __restrict__ W2,
    const unsigned short* __restrict__ Goff,
    const float* __restrict__ obias,
    float* __restrict__ out) {
  int pt = blockIdx.x, z = blockIdx.y;
  int ho = (pt & 7) * 16 + (pt >> 3);       // XCD-band swizzle: XCD gets 16 contiguous rows
  const unsigned short* xz = xbT + (size_t)z * QC;
  const unsigned short* Gf = Goff + (size_t)z * Pn * 32;

  __shared__ unsigned short Qs[256 * 64];   // W2 tile [o=256][64ck] swizzled (32 KB)
  __shared__ unsigned short Ss[128 * 64];   // sampled tile [p][64c] swizzled (16 KB)
  __shared__ float Sw4[128][3][4];
  __shared__ int   Sq4[128][3][4];          // corner row byte offsets (q*512)

  int tid = threadIdx.x;
  // ---- prologue: offsets -> bilinear weights + corner rows per (p,k) ----
  if (tid < 384) {
    int k = tid >> 7;                 // 0..2
    int wo = tid & 127;
    float offy = 0.f, offx = 0.f;
    int ocy = 2 * k, ocx = 2 * k + 1;
    if (ocy != 4) {
      float s = obias[ocy];
      #pragma unroll
      for (int kw = 0; kw < 3; ++kw) {
        int col = wo + kw - 1;
        if (col >= 0 && col < Wn)
          s += bf2f(Gf[(size_t)(ho * Wn + col) * 32 + ocy * 3 + kw]);
      }
      offy = s;
    }
    if (ocx != 1) {
      float s = obias[ocx];
      #pragma unroll
      for (int kw = 0; kw < 3; ++kw) {
        int col = wo + kw - 1;
        if (col >= 0 && col < Wn)
          s += bf2f(Gf[(size_t)(ho * Wn + col) * 32 + ocx * 3 + kw]);
      }
      offx = s;
    }
    float py = (float)ho + offy;
    float px = (float)(wo + k - 1) + offx;
    float y0f = floorf(py), x0f = floorf(px);
    float wy = py - y0f, wx = px - x0f;
    int y0 = (int)y0f, x0 = (int)x0f;
    int y1 = y0 + 1, x1 = x0 + 1;
    bool vy0 = (y0 >= 0) && (y0 < Hn), vy1 = (y1 >= 0) && (y1 < Hn);
    bool vx0 = (x0 >= 0) && (x0 < Wn), vx1 = (x1 >= 0) && (x1 < Wn);
    int yc0 = min(max(y0, 0), Hn - 1), yc1 = min(max(y1, 0), Hn - 1);
    int xc0 = min(max(x0, 0), Wn - 1), xc1 = min(max(x1, 0), Wn - 1);
    Sq4[wo][k][0] = (yc0 * Wn + xc0) * 512;
    Sq4[wo][k][1] = (yc0 * Wn + xc1) * 512;
    Sq4[wo][k][2] = (yc1 * Wn + xc0) * 512;
    Sq4[wo][k][3] = (yc1 * Wn + xc1) * 512;
    Sw4[wo][k][0] = (vy0 && vx0) ? (1.f - wy) * (1.f - wx) : 0.f;
    Sw4[wo][k][1] = (vy0 && vx1) ? (1.f - wy) * wx : 0.f;
    Sw4[wo][k][2] = (vy1 && vx0) ? wy * (1.f - wx) : 0.f;
    Sw4[wo][k][3] = (vy1 && vx1) ? wy * wx : 0.f;
  }

  int lane = tid & 63, wid = tid >> 6;
  int wr = wid >> 1, wc = wid & 1;          // wr: o-quarter (0..3), wc: p-half (0..1)
  int oct = tid & 7, pg = tid >> 3;         // staging: 8 octets x 64 p-groups
  f32x4 acc[4][4];
  #pragma unroll
  for (int m = 0; m < 4; ++m)
    #pragma unroll
    for (int n = 0; n < 4; ++n) acc[m][n] = (f32x4){0.f, 0.f, 0.f, 0.f};

  __syncthreads();   // Sw4/Sq4 ready

  for (int kt = 0; kt < 12; ++kt) {
    int k = kt >> 2;
    int c0 = (kt & 3) << 6;
    __syncthreads();                        // LDS free from previous MFMA reads
    // A: W2 o-rows (256 x 128B) via global_load_lds — L2-resident
    #pragma unroll
    for (int i = 0; i < 4; ++i) {
      int t = tid + i * 512;                // 0..2047
      int fo = t << 4;
      int row = fo >> 7;
      int slot = (fo >> 4) & 7;
      int ss = slot ^ (row & 7);
      gload_lds16(W2 + (size_t)row * W2ROW + k * 256 + c0 + ss * 8, (char*)Qs + fo);
    }
    // B: bilinear-sampled p-rows, reg-staged, swizzled ds_write
    const char* bse = (const char*)xz + (c0 + oct * 8) * 2;
    #pragma unroll
    for (int i = 0; i < 2; ++i) {
      int pl = pg + 64 * i;
      float w0 = Sw4[pl][k][0], w1 = Sw4[pl][k][1], w2 = Sw4[pl][k][2], w3 = Sw4[pl][k][3];
      uint4 v0 = *(const uint4*)(bse + Sq4[pl][k][0]);
      uint4 v1 = *(const uint4*)(bse + Sq4[pl][k][1]);
      uint4 v2 = *(const uint4*)(bse + Sq4[pl][k][2]);
      uint4 v3 = *(const uint4*)(bse + Sq4[pl][k][3]);
      float f[8] = {0.f, 0.f, 0.f, 0.f, 0.f, 0.f, 0.f, 0.f};
      bacc(v0, w0, f); bacc(v1, w1, f); bacc(v2, w2, f); bacc(v3, w3, f);
      uint4 r;
      r.x = (unsigned int)f2bf(f[0]) | ((unsigned int)f2bf(f[1]) << 16);
      r.y = (unsigned int)f2bf(f[2]) | ((unsigned int)f2bf(f[3]) << 16);
      r.z = (unsigned int)f2bf(f[4]) | ((unsigned int)f2bf(f[5]) << 16);
      r.w = (unsigned int)f2bf(f[6]) | ((unsigned int)f2bf(f[7]) << 16);
      *(uint4*)((char*)Ss + pl * 128 + ((oct ^ (pl & 7)) << 4)) = r;
    }
    __syncthreads();                        // A landed + B written
    #pragma unroll
    for (int s = 0; s < 2; ++s) {
      bf16x8 af[4], bfr[4];
      #pragma unroll
      for (int m = 0; m < 4; ++m) {
        int row = wr * 64 + m * 16 + (lane & 15);   // o-row 0..255
        int slot = (s * 4 + (lane >> 4)) ^ (row & 7);
        af[m] = *(const bf16x8*)((const char*)Qs + row * 128 + slot * 16);
      }
      #pragma unroll
      for (int n = 0; n < 4; ++n) {
        int row = wc * 64 + n * 16 + (lane & 15);   // p-row 0..127
        int slot = (s * 4 + (lane >> 4)) ^ (row & 7);
        bfr[n] = *(const bf16x8*)((const char*)Ss + row * 128 + slot * 16);
      }
      #pragma unroll
      for (int m = 0; m < 4; ++m)
        #pragma unroll
        for (int n = 0; n < 4; ++n)
          acc[m][n] = __builtin_amdgcn_mfma_f32_16x16x32_bf16(af[m], bfr[n], acc[m][n], 0, 0, 0);
    }
  }
  // C write: D row = o (A-operand), col = p
  float* ob_ = out + (size_t)z * On * Pn + (size_t)ho * Wn;
  #pragma unroll
  for (int m = 0; m < 4; ++m)
    #pragma unroll
    for (int n = 0; n < 4; ++n)
      #pragma unroll
      for (int rr = 0; rr < 4; ++rr) {
        int o = wr * 64 + m * 16 + (lane >> 4) * 4 + rr;
        int pc = wc * 64 + n * 16 + (lane & 15);
        ob_[(size_t)o * Pn + pc] = acc[m][n][rr];
      }
}

extern "C" void kernel_launch(void* const* d_in, const int* in_sizes, int n_in,
                              void* d_out, int out_size, void* d_ws, size_t ws_size,
                              hipStream_t stream) {
  const float* x  = (const float*)d_in[0];
  const float* ow = (const float*)d_in[1];
  const float* ob = (const float*)d_in[2];
  const float* dw = (const float*)d_in[3];
  float* out = (float*)d_out;

  char* ws = (char*)d_ws;
  size_t w2_bytes   = (size_t)On * W2ROW * 2;           // 384 KB
  size_t wbig_bytes = (size_t)Rpad * Cn * 2;            // 459 KB
  size_t xbT_bytes  = QC * 2;                           // 8.39 MB / batch
  size_t w2_al   = (w2_bytes + 255) & ~(size_t)255;
  size_t wbig_al = (wbig_bytes + 255) & ~(size_t)255;

  unsigned short* W2   = (unsigned short*)ws;
  unsigned short* Wbig = (unsigned short*)(ws + w2_al);
  unsigned short* xbT  = (unsigned short*)(ws + w2_al + wbig_al);
  unsigned short* Goff = (unsigned short*)(ws + w2_al + wbig_al + (size_t)Bn * xbT_bytes);
  (void)ws_size;

  k_wprep<<<Rpad, 256, 0, stream>>>(dw, ow, W2, Wbig);
  k_transpose<<<dim3(256, 4, Bn), 256, 0, stream>>>(x, xbT);
  k_goff<<<dim3(1, 128, Bn), 256, 0, stream>>>(xbT, Wbig, Goff);
  k_fgemm<<<dim3(128, Bn), 512, 0, stream>>>(xbT, W2, Goff, ob, out);
}

// Round 7
// 175.780 us; speedup vs baseline: 2.2495x; 1.0470x over previous
//
#include <hip/hip_runtime.h>
#include <hip/hip_bf16.h>

#define Bn 8
#define Cn 256
#define Hn 128
#define Wn 128
#define On 256
#define HWn (Hn*Wn)
#define Pn  HWn           // 16384 positions per batch
#define Rpad 896          // Wbig rows (768 deform unused here + 18 offset + pad)
#define W2ROW 768         // W2 row length (ck)
#define QC  ((size_t)Pn * Cn)

typedef __attribute__((ext_vector_type(8))) short bf16x8;
typedef __attribute__((ext_vector_type(4))) float f32x4;

__device__ __forceinline__ void gload_lds16(const void* g, void* l) {
  __builtin_amdgcn_global_load_lds(
      (__attribute__((address_space(1))) void*)g,
      (__attribute__((address_space(3))) void*)l, 16, 0, 0);
}

__device__ __forceinline__ unsigned short f2bf(float f) {
  unsigned int u = __float_as_uint(f);
  unsigned int r = (u + 0x7fffu + ((u >> 16) & 1u)) >> 16;
  return (unsigned short)r;
}
__device__ __forceinline__ float bf2f(unsigned short u) {
  return __uint_as_float(((unsigned int)u) << 16);
}
__device__ __forceinline__ void bacc(uint4 v, float w, float* f) {
  f[0] += w * __uint_as_float(v.x << 16);
  f[1] += w * __uint_as_float(v.x & 0xffff0000u);
  f[2] += w * __uint_as_float(v.y << 16);
  f[3] += w * __uint_as_float(v.y & 0xffff0000u);
  f[4] += w * __uint_as_float(v.z << 16);
  f[5] += w * __uint_as_float(v.z & 0xffff0000u);
  f[6] += w * __uint_as_float(v.w << 16);
  f[7] += w * __uint_as_float(v.w & 0xffff0000u);
}

// -------- Phase 0: W2[o][k*256+c] = dw[o][c][k]; Wbig[768+oc*3+kw][c] = ow[oc][c][kw] --------
__global__ __launch_bounds__(256) void k_wprep(
    const float* __restrict__ dw, const float* __restrict__ ow,
    unsigned short* __restrict__ W2, unsigned short* __restrict__ Wbig) {
  int r = blockIdx.x;          // 0..895
  int c = threadIdx.x;         // 0..255
  float v = 0.f;
  if (r < 768) {
    int k = r >> 8, o = r & 255;
    v = dw[((size_t)o * Cn + c) * 3 + k];
    W2[(size_t)o * W2ROW + k * 256 + c] = f2bf(v);
  } else if (r < 786) {
    int rr = r - 768;
    int oc = rr / 3, kw = rr - 3 * oc;
    v = ow[((size_t)oc * Cn + c) * 3 + kw];
  }
  Wbig[(size_t)r * Cn + c] = f2bf(v);
}

// -------- Phase 1: transpose+cast  xbT[z][q][c] bf16 <- x[b][c][q] fp32 --------
__global__ __launch_bounds__(256) void k_transpose(
    const float* __restrict__ x, unsigned short* __restrict__ xbT) {
  int b = blockIdx.z;
  int q0 = blockIdx.x * 64, c0 = blockIdx.y * 64;
  __shared__ unsigned short t[64][66];
  int tid = threadIdx.x;
  int qi = tid & 63, cg = tid >> 6;
  const float* xb = x + (size_t)b * Cn * HWn;
  #pragma unroll
  for (int i = 0; i < 16; ++i) {
    int cl = i * 4 + cg;
    t[cl][qi] = f2bf(xb[(size_t)(c0 + cl) * HWn + q0 + qi]);
  }
  __syncthreads();
  unsigned short* dst = xbT + (size_t)b * QC;
  int c2 = (tid & 31) * 2, qg = tid >> 5;
  #pragma unroll
  for (int j = 0; j < 8; ++j) {
    int ql = j * 8 + qg;
    unsigned int u = (unsigned int)t[c2][ql] | ((unsigned int)t[c2 + 1][ql] << 16);
    *(unsigned int*)(dst + (size_t)(q0 + ql) * Cn + c0 + c2) = u;
  }
}

// -------- Phase 2: Goff[z][q][j] = sum_c xbT[q][c] * Wbig[768+j][c], j<18 (bf16) --------
__global__ __launch_bounds__(256) void k_goff(
    const unsigned short* __restrict__ xbT,
    const unsigned short* __restrict__ Wbig,
    unsigned short* __restrict__ Goff) {
  int q0 = blockIdx.y * 128;
  const unsigned short* xb = xbT + (size_t)blockIdx.z * QC;
  unsigned short* Gz = Goff + (size_t)blockIdx.z * Pn * 32;
  __shared__ unsigned short Qs[128 * 64];
  __shared__ unsigned short Ws[128 * 64];
  int tid = threadIdx.x;
  int lane = tid & 63, wid = tid >> 6;
  int wr = wid >> 1, wc = wid & 1;
  f32x4 acc[4][4];
  #pragma unroll
  for (int m = 0; m < 4; ++m)
    #pragma unroll
    for (int n = 0; n < 4; ++n) acc[m][n] = (f32x4){0.f, 0.f, 0.f, 0.f};

  for (int kt = 0; kt < 4; ++kt) {
    int ck0 = kt * 64;
    __syncthreads();
    #pragma unroll
    for (int i = 0; i < 4; ++i) {
      int fo = wid * 1024 + i * 4096 + lane * 16;
      int row = fo >> 7;
      int slot = (fo >> 4) & 7;
      int ss = slot ^ (row & 7);
      gload_lds16(xb   + (size_t)(q0 + row) * Cn + ck0 + ss * 8, (char*)Qs + fo);
      gload_lds16(Wbig + (size_t)(768 + row) * Cn + ck0 + ss * 8, (char*)Ws + fo);
    }
    __syncthreads();
    #pragma unroll
    for (int s = 0; s < 2; ++s) {
      bf16x8 af[4], bfr[4];
      #pragma unroll
      for (int m = 0; m < 4; ++m) {
        int row = wr * 64 + m * 16 + (lane & 15);
        int slot = (s * 4 + (lane >> 4)) ^ (row & 7);
        af[m] = *(const bf16x8*)((const char*)Qs + row * 128 + slot * 16);
      }
      #pragma unroll
      for (int n = 0; n < 4; ++n) {
        int row = wc * 64 + n * 16 + (lane & 15);
        int slot = (s * 4 + (lane >> 4)) ^ (row & 7);
        bfr[n] = *(const bf16x8*)((const char*)Ws + row * 128 + slot * 16);
      }
      #pragma unroll
      for (int m = 0; m < 4; ++m)
        #pragma unroll
        for (int n = 0; n < 4; ++n)
          acc[m][n] = __builtin_amdgcn_mfma_f32_16x16x32_bf16(af[m], bfr[n], acc[m][n], 0, 0, 0);
    }
  }
  if (wc == 0) {
    #pragma unroll
    for (int m = 0; m < 4; ++m)
      #pragma unroll
      for (int n = 0; n < 2; ++n)
        #pragma unroll
        for (int rr = 0; rr < 4; ++rr) {
          int q = q0 + wr * 64 + m * 16 + (lane >> 4) * 4 + rr;
          int j = n * 16 + (lane & 15);
          if (j < 18) Gz[(size_t)q * 32 + j] = f2bf(acc[m][n][rr]);
        }
  }
}

// -------- Phase 3: fused sample+GEMM, 8 waves, full O=256 per block, gather-prefetch pipeline --------
__global__ __launch_bounds__(512) void k_fgemm(
    const unsigned short* __restrict__ xbT,
    const unsigned short* __restrict__ W2,
    const unsigned short* __restrict__ Goff,
    const float* __restrict__ obias,
    float* __restrict__ out) {
  int pt = blockIdx.x, z = blockIdx.y;
  int ho = (pt & 7) * 16 + (pt >> 3);       // XCD-band swizzle: XCD gets 16 contiguous rows
  const unsigned short* xz = xbT + (size_t)z * QC;
  const unsigned short* Gf = Goff + (size_t)z * Pn * 32;

  __shared__ unsigned short Qs[256 * 64];   // W2 tile [o=256][64ck] swizzled (32 KB)
  __shared__ unsigned short Ss[128 * 64];   // sampled tile [p][64c] swizzled (16 KB)
  __shared__ float Sw4[128][3][4];
  __shared__ int   Sq4[128][3][4];          // corner row byte offsets (q*512)

  int tid = threadIdx.x;
  // ---- prologue: offsets -> bilinear weights + corner rows per (p,k) ----
  if (tid < 384) {
    int k = tid >> 7;                 // 0..2
    int wo = tid & 127;
    float offy = 0.f, offx = 0.f;
    int ocy = 2 * k, ocx = 2 * k + 1;
    if (ocy != 4) {
      float s = obias[ocy];
      #pragma unroll
      for (int kw = 0; kw < 3; ++kw) {
        int col = wo + kw - 1;
        if (col >= 0 && col < Wn)
          s += bf2f(Gf[(size_t)(ho * Wn + col) * 32 + ocy * 3 + kw]);
      }
      offy = s;
    }
    if (ocx != 1) {
      float s = obias[ocx];
      #pragma unroll
      for (int kw = 0; kw < 3; ++kw) {
        int col = wo + kw - 1;
        if (col >= 0 && col < Wn)
          s += bf2f(Gf[(size_t)(ho * Wn + col) * 32 + ocx * 3 + kw]);
      }
      offx = s;
    }
    float py = (float)ho + offy;
    float px = (float)(wo + k - 1) + offx;
    float y0f = floorf(py), x0f = floorf(px);
    float wy = py - y0f, wx = px - x0f;
    int y0 = (int)y0f, x0 = (int)x0f;
    int y1 = y0 + 1, x1 = x0 + 1;
    bool vy0 = (y0 >= 0) && (y0 < Hn), vy1 = (y1 >= 0) && (y1 < Hn);
    bool vx0 = (x0 >= 0) && (x0 < Wn), vx1 = (x1 >= 0) && (x1 < Wn);
    int yc0 = min(max(y0, 0), Hn - 1), yc1 = min(max(y1, 0), Hn - 1);
    int xc0 = min(max(x0, 0), Wn - 1), xc1 = min(max(x1, 0), Wn - 1);
    Sq4[wo][k][0] = (yc0 * Wn + xc0) * 512;
    Sq4[wo][k][1] = (yc0 * Wn + xc1) * 512;
    Sq4[wo][k][2] = (yc1 * Wn + xc0) * 512;
    Sq4[wo][k][3] = (yc1 * Wn + xc1) * 512;
    Sw4[wo][k][0] = (vy0 && vx0) ? (1.f - wy) * (1.f - wx) : 0.f;
    Sw4[wo][k][1] = (vy0 && vx1) ? (1.f - wy) * wx : 0.f;
    Sw4[wo][k][2] = (vy1 && vx0) ? wy * (1.f - wx) : 0.f;
    Sw4[wo][k][3] = (vy1 && vx1) ? wy * wx : 0.f;
  }

  int lane = tid & 63, wid = tid >> 6;
  int wr = wid >> 1, wc = wid & 1;          // wr: o-quarter (0..3), wc: p-half (0..1)
  int oct = tid & 7, pg = tid >> 3;         // staging: 8 octets x 64 p-groups
  f32x4 acc[4][4];
  #pragma unroll
  for (int m = 0; m < 4; ++m)
    #pragma unroll
    for (int n = 0; n < 4; ++n) acc[m][n] = (f32x4){0.f, 0.f, 0.f, 0.f};

  __syncthreads();   // Sw4/Sq4 ready

  // pipeline registers: corners + weights for the CURRENT kt (2 positions x 4 corners)
  uint4 gA0, gA1, gA2, gA3, gB0, gB1, gB2, gB3;
  float wA0, wA1, wA2, wA3, wB0, wB1, wB2, wB3;
  int plA = pg, plB = pg + 64;

  #define PREF(KT) do {                                                   \
    int kk = (KT) >> 2, cc0 = ((KT) & 3) << 6;                            \
    const char* bse = (const char*)xz + (cc0 + oct * 8) * 2;              \
    wA0 = Sw4[plA][kk][0]; wA1 = Sw4[plA][kk][1];                         \
    wA2 = Sw4[plA][kk][2]; wA3 = Sw4[plA][kk][3];                         \
    wB0 = Sw4[plB][kk][0]; wB1 = Sw4[plB][kk][1];                         \
    wB2 = Sw4[plB][kk][2]; wB3 = Sw4[plB][kk][3];                         \
    gA0 = *(const uint4*)(bse + Sq4[plA][kk][0]);                         \
    gA1 = *(const uint4*)(bse + Sq4[plA][kk][1]);                         \
    gA2 = *(const uint4*)(bse + Sq4[plA][kk][2]);                         \
    gA3 = *(const uint4*)(bse + Sq4[plA][kk][3]);                         \
    gB0 = *(const uint4*)(bse + Sq4[plB][kk][0]);                         \
    gB1 = *(const uint4*)(bse + Sq4[plB][kk][1]);                         \
    gB2 = *(const uint4*)(bse + Sq4[plB][kk][2]);                         \
    gB3 = *(const uint4*)(bse + Sq4[plB][kk][3]);                         \
  } while (0)

  PREF(0);

  #pragma unroll
  for (int kt = 0; kt < 12; ++kt) {
    int k = kt >> 2;
    int c0 = (kt & 3) << 6;
    __syncthreads();                        // MFMA of kt-1 done; Qs/Ss free
    // A: W2 o-rows (256 x 128B) via global_load_lds — L2-resident
    #pragma unroll
    for (int i = 0; i < 4; ++i) {
      int t = tid + i * 512;                // 0..2047
      int fo = t << 4;
      int row = fo >> 7;
      int slot = (fo >> 4) & 7;
      int ss = slot ^ (row & 7);
      gload_lds16(W2 + (size_t)row * W2ROW + k * 256 + c0 + ss * 8, (char*)Qs + fo);
    }
    // B: bilinear combine from prefetched regs (pure VALU), swizzled ds_write
    {
      float f[8] = {0.f, 0.f, 0.f, 0.f, 0.f, 0.f, 0.f, 0.f};
      bacc(gA0, wA0, f); bacc(gA1, wA1, f); bacc(gA2, wA2, f); bacc(gA3, wA3, f);
      uint4 r;
      r.x = (unsigned int)f2bf(f[0]) | ((unsigned int)f2bf(f[1]) << 16);
      r.y = (unsigned int)f2bf(f[2]) | ((unsigned int)f2bf(f[3]) << 16);
      r.z = (unsigned int)f2bf(f[4]) | ((unsigned int)f2bf(f[5]) << 16);
      r.w = (unsigned int)f2bf(f[6]) | ((unsigned int)f2bf(f[7]) << 16);
      *(uint4*)((char*)Ss + plA * 128 + ((oct ^ (plA & 7)) << 4)) = r;
    }
    {
      float f[8] = {0.f, 0.f, 0.f, 0.f, 0.f, 0.f, 0.f, 0.f};
      bacc(gB0, wB0, f); bacc(gB1, wB1, f); bacc(gB2, wB2, f); bacc(gB3, wB3, f);
      uint4 r;
      r.x = (unsigned int)f2bf(f[0]) | ((unsigned int)f2bf(f[1]) << 16);
      r.y = (unsigned int)f2bf(f[2]) | ((unsigned int)f2bf(f[3]) << 16);
      r.z = (unsigned int)f2bf(f[4]) | ((unsigned int)f2bf(f[5]) << 16);
      r.w = (unsigned int)f2bf(f[6]) | ((unsigned int)f2bf(f[7]) << 16);
      *(uint4*)((char*)Ss + plB * 128 + ((oct ^ (plB & 7)) << 4)) = r;
    }
    // prefetch next K-step's corners: latency overlaps A-drain + MFMA below
    if (kt < 11) PREF(kt + 1);
    __syncthreads();                        // A landed + B written
    #pragma unroll
    for (int s = 0; s < 2; ++s) {
      bf16x8 af[4], bfr[4];
      #pragma unroll
      for (int m = 0; m < 4; ++m) {
        int row = wr * 64 + m * 16 + (lane & 15);   // o-row 0..255
        int slot = (s * 4 + (lane >> 4)) ^ (row & 7);
        af[m] = *(const bf16x8*)((const char*)Qs + row * 128 + slot * 16);
      }
      #pragma unroll
      for (int n = 0; n < 4; ++n) {
        int row = wc * 64 + n * 16 + (lane & 15);   // p-row 0..127
        int slot = (s * 4 + (lane >> 4)) ^ (row & 7);
        bfr[n] = *(const bf16x8*)((const char*)Ss + row * 128 + slot * 16);
      }
      #pragma unroll
      for (int m = 0; m < 4; ++m)
        #pragma unroll
        for (int n = 0; n < 4; ++n)
          acc[m][n] = __builtin_amdgcn_mfma_f32_16x16x32_bf16(af[m], bfr[n], acc[m][n], 0, 0, 0);
    }
  }
  #undef PREF
  // C write: D row = o (A-operand), col = p
  float* ob_ = out + (size_t)z * On * Pn + (size_t)ho * Wn;
  #pragma unroll
  for (int m = 0; m < 4; ++m)
    #pragma unroll
    for (int n = 0; n < 4; ++n)
      #pragma unroll
      for (int rr = 0; rr < 4; ++rr) {
        int o = wr * 64 + m * 16 + (lane >> 4) * 4 + rr;
        int pc = wc * 64 + n * 16 + (lane & 15);
        ob_[(size_t)o * Pn + pc] = acc[m][n][rr];
      }
}

extern "C" void kernel_launch(void* const* d_in, const int* in_sizes, int n_in,
                              void* d_out, int out_size, void* d_ws, size_t ws_size,
                              hipStream_t stream) {
  const float* x  = (const float*)d_in[0];
  const float* ow = (const float*)d_in[1];
  const float* ob = (const float*)d_in[2];
  const float* dw = (const float*)d_in[3];
  float* out = (float*)d_out;

  char* ws = (char*)d_ws;
  size_t w2_bytes   = (size_t)On * W2ROW * 2;           // 384 KB
  size_t wbig_bytes = (size_t)Rpad * Cn * 2;            // 459 KB
  size_t xbT_bytes  = QC * 2;                           // 8.39 MB / batch
  size_t w2_al   = (w2_bytes + 255) & ~(size_t)255;
  size_t wbig_al = (wbig_bytes + 255) & ~(size_t)255;

  unsigned short* W2   = (unsigned short*)ws;
  unsigned short* Wbig = (unsigned short*)(ws + w2_al);
  unsigned short* xbT  = (unsigned short*)(ws + w2_al + wbig_al);
  unsigned short* Goff = (unsigned short*)(ws + w2_al + wbig_al + (size_t)Bn * xbT_bytes);
  (void)ws_size;

  k_wprep<<<Rpad, 256, 0, stream>>>(dw, ow, W2, Wbig);
  k_transpose<<<dim3(256, 4, Bn), 256, 0, stream>>>(x, xbT);
  k_goff<<<dim3(1, 128, Bn), 256, 0, stream>>>(xbT, Wbig, Goff);
  k_fgemm<<<dim3(128, Bn), 512, 0, stream>>>(xbT, W2, Goff, ob, out);
}